// Round 9
// baseline (511.408 us; speedup 1.0000x reference)
//
#include <hip/hip_runtime.h>

// GraphConvModel: 2x GraphConv(norm='both') + 2x Linear+LeakyReLU
// N=50000 nodes, E=800000 edges, feats 128 -> 128 -> 128 -> 256 -> 40 (f32)
// G = X@W first (graph-independent), then normalized gather with fused
// bias+relu. Degree/rank atomics in specialized blocks of the first GEMM
// launch (R6 structure). Scan fused to a single 1-block kernel.

typedef __attribute__((ext_vector_type(8))) short short8v;
typedef __attribute__((ext_vector_type(4))) float f32x4;

// ---------------- fused exclusive scan + inv-degree (one block) ----------------
__global__ __launch_bounds__(1024) void k_scan_all(const int* __restrict__ deg_in,
                                                   const int* __restrict__ deg_out,
                                                   int* __restrict__ row_ptr,
                                                   float* __restrict__ inv_in,
                                                   float* __restrict__ inv_out,
                                                   int N, int E) {
    __shared__ int s[1024];
    int t = threadIdx.x;
    int chunk = (N + 1023) / 1024;
    int lo = t * chunk, hi = min(N, lo + chunk);
    int c = 0;
    for (int i = lo; i < hi; ++i) c += deg_in[i];
    s[t] = c; __syncthreads();
    for (int o = 1; o < 1024; o <<= 1) {
        int x = (t >= o) ? s[t - o] : 0;
        __syncthreads();
        s[t] += x;
        __syncthreads();
    }
    int base = (t > 0) ? s[t - 1] : 0;   // exclusive prefix of this chunk
    for (int i = lo; i < hi; ++i) {
        int di = deg_in[i];
        row_ptr[i] = base;
        base += di;
        inv_in[i]  = rsqrtf(fmaxf((float)di, 1.0f));
        inv_out[i] = rsqrtf(fmaxf((float)deg_out[i], 1.0f));
    }
    if (t == 0) row_ptr[N] = E;
}

// ---------------- CSR scatter (no atomics: rank precomputed) ----------------
__global__ void k_scatter3(const int* __restrict__ src, const int* __restrict__ dst,
                           const int* __restrict__ row_ptr, const int* __restrict__ rank,
                           const float* __restrict__ inv_out,
                           int2* __restrict__ edges, int E) {
    int i = blockIdx.x * blockDim.x + threadIdx.x;
    if (i < E) {
        int s = src[i];
        int2 p;
        p.x = s;
        p.y = __float_as_int(inv_out[s]);
        edges[row_ptr[dst[i]] + rank[i]] = p;
    }
}

// ---------------- SpMM gather + bias + relu ----------------
// Y[i,:] = relu(inv_in[i] * sum_e sc_e * X[s_e,:] + bias)
__global__ void k_gather2(const float* __restrict__ X, const int2* __restrict__ edges,
                          const int* __restrict__ row_ptr, const float* __restrict__ inv_in,
                          const float* __restrict__ bias, float* __restrict__ Y, int N) {
    int lane = threadIdx.x & 31;
    int row = blockIdx.x * 8 + (threadIdx.x >> 5);
    if (row >= N) return;
    int rs = row_ptr[row], re = row_ptr[row + 1];
    float4 acc = {0.f, 0.f, 0.f, 0.f};
    int e = rs;
    #define LDROW(s) (*reinterpret_cast<const float4*>(&X[(size_t)(s) * 128 + lane * 4]))
    for (; e + 8 <= re; e += 8) {
        int2 p0 = edges[e],     p1 = edges[e + 1], p2 = edges[e + 2], p3 = edges[e + 3];
        int2 p4 = edges[e + 4], p5 = edges[e + 5], p6 = edges[e + 6], p7 = edges[e + 7];
        float4 x0 = LDROW(p0.x), x1 = LDROW(p1.x), x2 = LDROW(p2.x), x3 = LDROW(p3.x);
        float4 x4 = LDROW(p4.x), x5 = LDROW(p5.x), x6 = LDROW(p6.x), x7 = LDROW(p7.x);
        float c0 = __int_as_float(p0.y), c1 = __int_as_float(p1.y);
        float c2 = __int_as_float(p2.y), c3 = __int_as_float(p3.y);
        float c4 = __int_as_float(p4.y), c5 = __int_as_float(p5.y);
        float c6 = __int_as_float(p6.y), c7 = __int_as_float(p7.y);
        acc.x += c0*x0.x + c1*x1.x + c2*x2.x + c3*x3.x + c4*x4.x + c5*x5.x + c6*x6.x + c7*x7.x;
        acc.y += c0*x0.y + c1*x1.y + c2*x2.y + c3*x3.y + c4*x4.y + c5*x5.y + c6*x6.y + c7*x7.y;
        acc.z += c0*x0.z + c1*x1.z + c2*x2.z + c3*x3.z + c4*x4.z + c5*x5.z + c6*x6.z + c7*x7.z;
        acc.w += c0*x0.w + c1*x1.w + c2*x2.w + c3*x3.w + c4*x4.w + c5*x5.w + c6*x6.w + c7*x7.w;
    }
    for (; e + 4 <= re; e += 4) {
        int2 p0 = edges[e], p1 = edges[e + 1], p2 = edges[e + 2], p3 = edges[e + 3];
        float4 x0 = LDROW(p0.x), x1 = LDROW(p1.x), x2 = LDROW(p2.x), x3 = LDROW(p3.x);
        float c0 = __int_as_float(p0.y), c1 = __int_as_float(p1.y);
        float c2 = __int_as_float(p2.y), c3 = __int_as_float(p3.y);
        acc.x += c0*x0.x + c1*x1.x + c2*x2.x + c3*x3.x;
        acc.y += c0*x0.y + c1*x1.y + c2*x2.y + c3*x3.y;
        acc.z += c0*x0.z + c1*x1.z + c2*x2.z + c3*x3.z;
        acc.w += c0*x0.w + c1*x1.w + c2*x2.w + c3*x3.w;
    }
    for (; e < re; ++e) {
        int2 p = edges[e];
        float c = __int_as_float(p.y);
        float4 xv = LDROW(p.x);
        acc.x += c * xv.x; acc.y += c * xv.y; acc.z += c * xv.z; acc.w += c * xv.w;
    }
    #undef LDROW
    float si = inv_in[row];
    float4 b4 = *reinterpret_cast<const float4*>(&bias[lane * 4]);
    float4 o;
    o.x = fmaxf(fmaf(acc.x, si, b4.x), 0.f);
    o.y = fmaxf(fmaf(acc.y, si, b4.y), 0.f);
    o.z = fmaxf(fmaf(acc.z, si, b4.z), 0.f);
    o.w = fmaxf(fmaf(acc.w, si, b4.w), 0.f);
    *reinterpret_cast<float4*>(&Y[(size_t)row * 128 + lane * 4]) = o;
}

// ---------------- bf16 split helpers ----------------
__device__ inline unsigned short bf16_rne(float f) {
    unsigned int u = __float_as_uint(f);
    u += 0x7fffu + ((u >> 16) & 1u);
    return (unsigned short)(u >> 16);
}

__device__ inline void split1(float a, unsigned short& h, unsigned short& l) {
    unsigned short hh = bf16_rne(a);
    float hf = __uint_as_float((unsigned int)hh << 16);
    l = bf16_rne(a - hf);
    h = hh;
}

// ---------------- MFMA GEMM: C = act(A[M,K] @ W[K,N] + bias) ----------------
// 256 threads = 4 waves (2x2). BM=128, 64-col tiles, full-K W staged once,
// A staged per BK=32. LDS XOR-swizzle: byte ^= (row&7)<<4.
// f32 emulated: a = ah + al (bf16), acc += ah*bh + ah*bl + al*bh.
// ACT: 0 = bias+relu, 1 = bias+leaky(0.01), 2 = raw (no bias).
// DEG: blocks [0, degb) run only the degree/rank atomic loop and exit.
template<int K, int N, int ACT, bool DEG>
__global__ __launch_bounds__(256) void k_gemm_mfma(const float* __restrict__ A,
                                                   const float* __restrict__ W,
                                                   const float* __restrict__ bias,
                                                   float* __restrict__ C, int M,
                                                   const int* __restrict__ src,
                                                   const int* __restrict__ dst,
                                                   int* __restrict__ deg_out,
                                                   int* __restrict__ deg_in,
                                                   int* __restrict__ rank, int E, int epb,
                                                   int gmm, int degb) {
    __shared__ unsigned short Bh[64 * K], Bl[64 * K];   // [col][k]
    __shared__ unsigned short Ah[128 * 32], Al[128 * 32];

    int t = threadIdx.x;
    int m0, cb;
    if (DEG) {
        int bid = blockIdx.x;
        if (bid < degb) {
            int base = bid * epb;
            int end = min(E, base + epb);
            for (int i = base + t; i < end; i += 256) {
                atomicAdd(&deg_out[src[i]], 1);
                rank[i] = atomicAdd(&deg_in[dst[i]], 1);
            }
            return;
        }
        int tile = bid - degb;
        m0 = (tile % gmm) * 128;
        cb = (tile / gmm) * 64;
    } else {
        m0 = blockIdx.x * 128;
        cb = blockIdx.y * 64;
    }

    // ---- stage W for full K (once) ----
    {
        int c = t & 63;
        int kb = (t >> 6) * (K / 4);
        bool cok = (N % 64 == 0) || (cb + c < N);
        for (int j = 0; j < K / 4; ++j) {
            int k = kb + j;
            float v = cok ? W[(size_t)k * N + cb + c] : 0.f;
            unsigned short hi, lo; split1(v, hi, lo);
            int byte = (c * 2 * K + 2 * k) ^ ((c & 7) << 4);
            Bh[byte >> 1] = hi;
            Bl[byte >> 1] = lo;
        }
    }

    f32x4 acc[4][2];
    #pragma unroll
    for (int i = 0; i < 4; ++i)
        #pragma unroll
        for (int j = 0; j < 2; ++j)
            acc[i][j] = (f32x4){0.f, 0.f, 0.f, 0.f};

    int lane = t & 63;
    int wave = t >> 6;
    int wm = wave >> 1, wn = wave & 1;
    int lr = lane & 15, lg = lane >> 4;

    for (int kt = 0; kt < K / 32; ++kt) {
        __syncthreads();
        // ---- stage A tile: 128 rows x 32 k ----
        #pragma unroll
        for (int i = 0; i < 4; ++i) {
            int g = i * 256 + t;
            int r = g >> 3;
            int kq = (g & 7) * 4;
            int gr = m0 + r;
            float4 v = {0.f, 0.f, 0.f, 0.f};
            if (gr < M) v = *reinterpret_cast<const float4*>(&A[(size_t)gr * K + kt * 32 + kq]);
            ushort4 h4, l4;
            split1(v.x, h4.x, l4.x);
            split1(v.y, h4.y, l4.y);
            split1(v.z, h4.z, l4.z);
            split1(v.w, h4.w, l4.w);
            int byte = (r * 64 + 2 * kq) ^ ((r & 7) << 4);
            *reinterpret_cast<ushort4*>(&Ah[byte >> 1]) = h4;
            *reinterpret_cast<ushort4*>(&Al[byte >> 1]) = l4;
        }
        __syncthreads();

        short8v bhf[2], blf[2];
        #pragma unroll
        for (int nf = 0; nf < 2; ++nf) {
            int c = wn * 32 + nf * 16 + lr;
            int byte = (c * 2 * K + 2 * (kt * 32 + lg * 8)) ^ ((c & 7) << 4);
            bhf[nf] = *reinterpret_cast<const short8v*>(&Bh[byte >> 1]);
            blf[nf] = *reinterpret_cast<const short8v*>(&Bl[byte >> 1]);
        }
        #pragma unroll
        for (int mf = 0; mf < 4; ++mf) {
            int r = wm * 64 + mf * 16 + lr;
            int byte = (r * 64 + 2 * (lg * 8)) ^ ((r & 7) << 4);
            short8v ahf = *reinterpret_cast<const short8v*>(&Ah[byte >> 1]);
            short8v alf = *reinterpret_cast<const short8v*>(&Al[byte >> 1]);
            #pragma unroll
            for (int nf = 0; nf < 2; ++nf) {
                acc[mf][nf] = __builtin_amdgcn_mfma_f32_16x16x32_bf16(ahf, bhf[nf], acc[mf][nf], 0, 0, 0);
                acc[mf][nf] = __builtin_amdgcn_mfma_f32_16x16x32_bf16(ahf, blf[nf], acc[mf][nf], 0, 0, 0);
                acc[mf][nf] = __builtin_amdgcn_mfma_f32_16x16x32_bf16(alf, bhf[nf], acc[mf][nf], 0, 0, 0);
            }
        }
    }

    // ---- epilogue: C/D layout col=lane&15, row=(lane>>4)*4+reg ----
    #pragma unroll
    for (int mf = 0; mf < 4; ++mf) {
        #pragma unroll
        for (int nf = 0; nf < 2; ++nf) {
            int col = cb + wn * 32 + nf * 16 + lr;
            if ((N % 64 != 0) && col >= N) continue;
            float bv = (ACT < 2) ? bias[col] : 0.f;
            #pragma unroll
            for (int rg = 0; rg < 4; ++rg) {
                int row = m0 + wm * 64 + mf * 16 + lg * 4 + rg;
                if (row < M) {
                    float v = acc[mf][nf][rg];
                    if (ACT == 0) v = fmaxf(v + bv, 0.f);
                    else if (ACT == 1) { v += bv; v = (v > 0.f) ? v : 0.01f * v; }
                    C[(size_t)row * N + col] = v;
                }
            }
        }
    }
}

extern "C" void kernel_launch(void* const* d_in, const int* in_sizes, int n_in,
                              void* d_out, int out_size, void* d_ws, size_t ws_size,
                              hipStream_t stream) {
    const float* feat = (const float*)d_in[0];
    const int*   src  = (const int*)d_in[1];
    const int*   dst  = (const int*)d_in[2];
    const float* W1   = (const float*)d_in[3];
    const float* b1   = (const float*)d_in[4];
    const float* W2   = (const float*)d_in[5];
    const float* b2   = (const float*)d_in[6];
    const float* Wd1  = (const float*)d_in[7];
    const float* bd1  = (const float*)d_in[8];
    const float* Wd2  = (const float*)d_in[9];
    const float* bd2  = (const float*)d_in[10];
    float* out = (float*)d_out;

    const int N = in_sizes[0] / 128;   // 50000
    const int E = in_sizes[1];         // 800000

    char* ws = (char*)d_ws;
    size_t off = 0;
    auto alloc = [&](size_t bytes) -> void* {
        void* p = ws + off;
        off += (bytes + 255) & ~(size_t)255;
        return p;
    };
    int* deg_out  = (int*)alloc((size_t)N * 4);
    int* deg_in   = (int*)alloc((size_t)N * 4);
    int* row_ptr  = (int*)alloc((size_t)(N + 1) * 4);
    int* rank     = (int*)alloc((size_t)E * 4);
    int2* edges   = (int2*)alloc((size_t)E * 8);
    float* inv_out = (float*)alloc((size_t)N * 4);
    float* inv_in  = (float*)alloc((size_t)N * 4);
    float* bufA = (float*)alloc((size_t)N * 128 * 4);   // G1, then G2
    float* bufB = (float*)alloc((size_t)N * 128 * 4);   // h1, then h2
    float* hd   = (float*)alloc((size_t)N * 256 * 4);

    // zero deg_out, deg_in (contiguous span)
    size_t zspan = (char*)deg_in + (size_t)N * 4 - (char*)deg_out;
    hipMemsetAsync(deg_out, 0, zspan, stream);

    int gE = (E + 255) / 256;
    int gG = (N + 7) / 8;
    int gMM = (N + 127) / 128;         // MFMA M-tiles

    // fused launch: blocks [0,DEGB) = degree/rank atomics; rest = G1 = feat@W1.
    const int DEGB = 512;
    int epb = (E + DEGB - 1) / DEGB;
    k_gemm_mfma<128, 128, 2, true><<<DEGB + gMM * 2, 256, 0, stream>>>(
        feat, W1, nullptr, bufA, N, src, dst, deg_out, deg_in, rank, E, epb, gMM, DEGB);

    k_scan_all<<<1, 1024, 0, stream>>>(deg_in, deg_out, row_ptr, inv_in, inv_out, N, E);
    k_scatter3<<<gE, 256, 0, stream>>>(src, dst, row_ptr, rank, inv_out, edges, E);

    // layer 1 gather: h1 = relu(norm-agg(G1) + b1)
    k_gather2<<<gG, 256, 0, stream>>>(bufA, edges, row_ptr, inv_in, b1, bufB, N);
    // layer 2: G2 = h1 @ W2 ; h2 = relu(norm-agg(G2) + b2)
    k_gemm_mfma<128, 128, 2, false><<<dim3(gMM, 2), 256, 0, stream>>>(
        bufB, W2, nullptr, bufA, N, nullptr, nullptr, nullptr, nullptr, nullptr, 0, 0, 0, 0);
    k_gather2<<<gG, 256, 0, stream>>>(bufA, edges, row_ptr, inv_in, b2, bufB, N);
    // DNN
    k_gemm_mfma<128, 256, 1, false><<<dim3(gMM, 4), 256, 0, stream>>>(
        bufB, Wd1, bd1, hd, N, nullptr, nullptr, nullptr, nullptr, nullptr, 0, 0, 0, 0);
    k_gemm_mfma<256, 40, 1, false><<<dim3(gMM, 1), 256, 0, stream>>>(
        hd, Wd2, bd2, out, N, nullptr, nullptr, nullptr, nullptr, nullptr, 0, 0, 0, 0);
}

// Round 10
// 337.233 us; speedup vs baseline: 1.5165x; 1.5165x over previous
//
#include <hip/hip_runtime.h>

// GraphConvModel: 2x GraphConv(norm='both') + 2x Linear+LeakyReLU
// N=50000 nodes, E=800000 edges, feats 128 -> 128 -> 128 -> 256 -> 40 (f32)
// G = X@W first (graph-independent), then normalized gather with fused
// bias+relu. Degree/rank atomics in specialized blocks of the first GEMM
// launch. 3-kernel scan (R9's single-block scan was latency-bound: 186us).

#define SCAN_B 256

typedef __attribute__((ext_vector_type(8))) short short8v;
typedef __attribute__((ext_vector_type(4))) float f32x4;

// ---------------- exclusive scan of deg_in -> row_ptr ----------------
__global__ void k_scanA(const int* __restrict__ deg_in, int* __restrict__ incl,
                        int* __restrict__ bsum, int N) {
    __shared__ int s[SCAN_B];
    int t = threadIdx.x, i = blockIdx.x * SCAN_B + t;
    int v = (i < N) ? deg_in[i] : 0;
    s[t] = v; __syncthreads();
    for (int o = 1; o < SCAN_B; o <<= 1) {
        int x = (t >= o) ? s[t - o] : 0;
        __syncthreads();
        s[t] += x;
        __syncthreads();
    }
    if (i < N) incl[i] = s[t];
    if (t == SCAN_B - 1) bsum[blockIdx.x] = s[t];
}

__global__ void k_scanB(int* __restrict__ bsum, int NB) {
    __shared__ int s[SCAN_B];
    int t = threadIdx.x;
    int v = (t < NB) ? bsum[t] : 0;
    s[t] = v; __syncthreads();
    for (int o = 1; o < SCAN_B; o <<= 1) {
        int x = (t >= o) ? s[t - o] : 0;
        __syncthreads();
        s[t] += x;
        __syncthreads();
    }
    if (t < NB) bsum[t] = s[t] - v;  // exclusive
}

__global__ void k_scanC(const int* __restrict__ deg_in, const int* __restrict__ deg_out,
                        int* __restrict__ row_ptr, const int* __restrict__ bsum,
                        float* __restrict__ inv_in, float* __restrict__ inv_out,
                        int N, int E) {
    int t = threadIdx.x, i = blockIdx.x * SCAN_B + t;
    if (i < N) {
        int di = deg_in[i];
        row_ptr[i] = row_ptr[i] - di + bsum[blockIdx.x];
        inv_in[i]  = rsqrtf(fmaxf((float)di, 1.0f));
        inv_out[i] = rsqrtf(fmaxf((float)deg_out[i], 1.0f));
    }
    if (i == 0) row_ptr[N] = E;
}

// ---------------- CSR scatter (no atomics: rank precomputed) ----------------
__global__ void k_scatter3(const int* __restrict__ src, const int* __restrict__ dst,
                           const int* __restrict__ row_ptr, const int* __restrict__ rank,
                           const float* __restrict__ inv_out,
                           int2* __restrict__ edges, int E) {
    int i = blockIdx.x * blockDim.x + threadIdx.x;
    if (i < E) {
        int s = src[i];
        int2 p;
        p.x = s;
        p.y = __float_as_int(inv_out[s]);
        edges[row_ptr[dst[i]] + rank[i]] = p;
    }
}

// ---------------- SpMM gather + bias + relu ----------------
// Y[i,:] = relu(inv_in[i] * sum_e sc_e * X[s_e,:] + bias)
__global__ void k_gather2(const float* __restrict__ X, const int2* __restrict__ edges,
                          const int* __restrict__ row_ptr, const float* __restrict__ inv_in,
                          const float* __restrict__ bias, float* __restrict__ Y, int N) {
    int lane = threadIdx.x & 31;
    int row = blockIdx.x * 8 + (threadIdx.x >> 5);
    if (row >= N) return;
    int rs = row_ptr[row], re = row_ptr[row + 1];
    float4 acc = {0.f, 0.f, 0.f, 0.f};
    int e = rs;
    #define LDROW(s) (*reinterpret_cast<const float4*>(&X[(size_t)(s) * 128 + lane * 4]))
    for (; e + 8 <= re; e += 8) {
        int2 p0 = edges[e],     p1 = edges[e + 1], p2 = edges[e + 2], p3 = edges[e + 3];
        int2 p4 = edges[e + 4], p5 = edges[e + 5], p6 = edges[e + 6], p7 = edges[e + 7];
        float4 x0 = LDROW(p0.x), x1 = LDROW(p1.x), x2 = LDROW(p2.x), x3 = LDROW(p3.x);
        float4 x4 = LDROW(p4.x), x5 = LDROW(p5.x), x6 = LDROW(p6.x), x7 = LDROW(p7.x);
        float c0 = __int_as_float(p0.y), c1 = __int_as_float(p1.y);
        float c2 = __int_as_float(p2.y), c3 = __int_as_float(p3.y);
        float c4 = __int_as_float(p4.y), c5 = __int_as_float(p5.y);
        float c6 = __int_as_float(p6.y), c7 = __int_as_float(p7.y);
        acc.x += c0*x0.x + c1*x1.x + c2*x2.x + c3*x3.x + c4*x4.x + c5*x5.x + c6*x6.x + c7*x7.x;
        acc.y += c0*x0.y + c1*x1.y + c2*x2.y + c3*x3.y + c4*x4.y + c5*x5.y + c6*x6.y + c7*x7.y;
        acc.z += c0*x0.z + c1*x1.z + c2*x2.z + c3*x3.z + c4*x4.z + c5*x5.z + c6*x6.z + c7*x7.z;
        acc.w += c0*x0.w + c1*x1.w + c2*x2.w + c3*x3.w + c4*x4.w + c5*x5.w + c6*x6.w + c7*x7.w;
    }
    for (; e + 4 <= re; e += 4) {
        int2 p0 = edges[e], p1 = edges[e + 1], p2 = edges[e + 2], p3 = edges[e + 3];
        float4 x0 = LDROW(p0.x), x1 = LDROW(p1.x), x2 = LDROW(p2.x), x3 = LDROW(p3.x);
        float c0 = __int_as_float(p0.y), c1 = __int_as_float(p1.y);
        float c2 = __int_as_float(p2.y), c3 = __int_as_float(p3.y);
        acc.x += c0*x0.x + c1*x1.x + c2*x2.x + c3*x3.x;
        acc.y += c0*x0.y + c1*x1.y + c2*x2.y + c3*x3.y;
        acc.z += c0*x0.z + c1*x1.z + c2*x2.z + c3*x3.z;
        acc.w += c0*x0.w + c1*x1.w + c2*x2.w + c3*x3.w;
    }
    for (; e < re; ++e) {
        int2 p = edges[e];
        float c = __int_as_float(p.y);
        float4 xv = LDROW(p.x);
        acc.x += c * xv.x; acc.y += c * xv.y; acc.z += c * xv.z; acc.w += c * xv.w;
    }
    #undef LDROW
    float si = inv_in[row];
    float4 b4 = *reinterpret_cast<const float4*>(&bias[lane * 4]);
    float4 o;
    o.x = fmaxf(fmaf(acc.x, si, b4.x), 0.f);
    o.y = fmaxf(fmaf(acc.y, si, b4.y), 0.f);
    o.z = fmaxf(fmaf(acc.z, si, b4.z), 0.f);
    o.w = fmaxf(fmaf(acc.w, si, b4.w), 0.f);
    *reinterpret_cast<float4*>(&Y[(size_t)row * 128 + lane * 4]) = o;
}

// ---------------- bf16 split helpers ----------------
__device__ inline unsigned short bf16_rne(float f) {
    unsigned int u = __float_as_uint(f);
    u += 0x7fffu + ((u >> 16) & 1u);
    return (unsigned short)(u >> 16);
}

__device__ inline void split1(float a, unsigned short& h, unsigned short& l) {
    unsigned short hh = bf16_rne(a);
    float hf = __uint_as_float((unsigned int)hh << 16);
    l = bf16_rne(a - hf);
    h = hh;
}

// ---------------- MFMA GEMM: C = act(A[M,K] @ W[K,N] + bias) ----------------
// 256 threads = 4 waves (2x2). BM=128, 64-col tiles, full-K W staged once,
// A staged per BK=32. LDS XOR-swizzle: byte ^= (row&7)<<4.
// f32 emulated: a = ah + al (bf16), acc += ah*bh + ah*bl + al*bh.
// ACT: 0 = bias+relu, 1 = bias+leaky(0.01), 2 = raw (no bias).
// DEG: blocks [0, degb) run only the degree/rank atomic loop and exit.
template<int K, int N, int ACT, bool DEG>
__global__ __launch_bounds__(256) void k_gemm_mfma(const float* __restrict__ A,
                                                   const float* __restrict__ W,
                                                   const float* __restrict__ bias,
                                                   float* __restrict__ C, int M,
                                                   const int* __restrict__ src,
                                                   const int* __restrict__ dst,
                                                   int* __restrict__ deg_out,
                                                   int* __restrict__ deg_in,
                                                   int* __restrict__ rank, int E, int epb,
                                                   int gmm, int degb) {
    __shared__ unsigned short Bh[64 * K], Bl[64 * K];   // [col][k]
    __shared__ unsigned short Ah[128 * 32], Al[128 * 32];

    int t = threadIdx.x;
    int m0, cb;
    if (DEG) {
        int bid = blockIdx.x;
        if (bid < degb) {
            int base = bid * epb;
            int end = min(E, base + epb);
            for (int i = base + t; i < end; i += 256) {
                atomicAdd(&deg_out[src[i]], 1);
                rank[i] = atomicAdd(&deg_in[dst[i]], 1);
            }
            return;
        }
        int tile = bid - degb;
        m0 = (tile % gmm) * 128;
        cb = (tile / gmm) * 64;
    } else {
        m0 = blockIdx.x * 128;
        cb = blockIdx.y * 64;
    }

    // ---- stage W for full K (once) ----
    {
        int c = t & 63;
        int kb = (t >> 6) * (K / 4);
        bool cok = (N % 64 == 0) || (cb + c < N);
        for (int j = 0; j < K / 4; ++j) {
            int k = kb + j;
            float v = cok ? W[(size_t)k * N + cb + c] : 0.f;
            unsigned short hi, lo; split1(v, hi, lo);
            int byte = (c * 2 * K + 2 * k) ^ ((c & 7) << 4);
            Bh[byte >> 1] = hi;
            Bl[byte >> 1] = lo;
        }
    }

    f32x4 acc[4][2];
    #pragma unroll
    for (int i = 0; i < 4; ++i)
        #pragma unroll
        for (int j = 0; j < 2; ++j)
            acc[i][j] = (f32x4){0.f, 0.f, 0.f, 0.f};

    int lane = t & 63;
    int wave = t >> 6;
    int wm = wave >> 1, wn = wave & 1;
    int lr = lane & 15, lg = lane >> 4;

    for (int kt = 0; kt < K / 32; ++kt) {
        __syncthreads();
        // ---- stage A tile: 128 rows x 32 k ----
        #pragma unroll
        for (int i = 0; i < 4; ++i) {
            int g = i * 256 + t;
            int r = g >> 3;
            int kq = (g & 7) * 4;
            int gr = m0 + r;
            float4 v = {0.f, 0.f, 0.f, 0.f};
            if (gr < M) v = *reinterpret_cast<const float4*>(&A[(size_t)gr * K + kt * 32 + kq]);
            ushort4 h4, l4;
            split1(v.x, h4.x, l4.x);
            split1(v.y, h4.y, l4.y);
            split1(v.z, h4.z, l4.z);
            split1(v.w, h4.w, l4.w);
            int byte = (r * 64 + 2 * kq) ^ ((r & 7) << 4);
            *reinterpret_cast<ushort4*>(&Ah[byte >> 1]) = h4;
            *reinterpret_cast<ushort4*>(&Al[byte >> 1]) = l4;
        }
        __syncthreads();

        short8v bhf[2], blf[2];
        #pragma unroll
        for (int nf = 0; nf < 2; ++nf) {
            int c = wn * 32 + nf * 16 + lr;
            int byte = (c * 2 * K + 2 * (kt * 32 + lg * 8)) ^ ((c & 7) << 4);
            bhf[nf] = *reinterpret_cast<const short8v*>(&Bh[byte >> 1]);
            blf[nf] = *reinterpret_cast<const short8v*>(&Bl[byte >> 1]);
        }
        #pragma unroll
        for (int mf = 0; mf < 4; ++mf) {
            int r = wm * 64 + mf * 16 + lr;
            int byte = (r * 64 + 2 * (lg * 8)) ^ ((r & 7) << 4);
            short8v ahf = *reinterpret_cast<const short8v*>(&Ah[byte >> 1]);
            short8v alf = *reinterpret_cast<const short8v*>(&Al[byte >> 1]);
            #pragma unroll
            for (int nf = 0; nf < 2; ++nf) {
                acc[mf][nf] = __builtin_amdgcn_mfma_f32_16x16x32_bf16(ahf, bhf[nf], acc[mf][nf], 0, 0, 0);
                acc[mf][nf] = __builtin_amdgcn_mfma_f32_16x16x32_bf16(ahf, blf[nf], acc[mf][nf], 0, 0, 0);
                acc[mf][nf] = __builtin_amdgcn_mfma_f32_16x16x32_bf16(alf, bhf[nf], acc[mf][nf], 0, 0, 0);
            }
        }
    }

    // ---- epilogue: C/D layout col=lane&15, row=(lane>>4)*4+reg ----
    #pragma unroll
    for (int mf = 0; mf < 4; ++mf) {
        #pragma unroll
        for (int nf = 0; nf < 2; ++nf) {
            int col = cb + wn * 32 + nf * 16 + lr;
            if ((N % 64 != 0) && col >= N) continue;
            float bv = (ACT < 2) ? bias[col] : 0.f;
            #pragma unroll
            for (int rg = 0; rg < 4; ++rg) {
                int row = m0 + wm * 64 + mf * 16 + lg * 4 + rg;
                if (row < M) {
                    float v = acc[mf][nf][rg];
                    if (ACT == 0) v = fmaxf(v + bv, 0.f);
                    else if (ACT == 1) { v += bv; v = (v > 0.f) ? v : 0.01f * v; }
                    C[(size_t)row * N + col] = v;
                }
            }
        }
    }
}

extern "C" void kernel_launch(void* const* d_in, const int* in_sizes, int n_in,
                              void* d_out, int out_size, void* d_ws, size_t ws_size,
                              hipStream_t stream) {
    const float* feat = (const float*)d_in[0];
    const int*   src  = (const int*)d_in[1];
    const int*   dst  = (const int*)d_in[2];
    const float* W1   = (const float*)d_in[3];
    const float* b1   = (const float*)d_in[4];
    const float* W2   = (const float*)d_in[5];
    const float* b2   = (const float*)d_in[6];
    const float* Wd1  = (const float*)d_in[7];
    const float* bd1  = (const float*)d_in[8];
    const float* Wd2  = (const float*)d_in[9];
    const float* bd2  = (const float*)d_in[10];
    float* out = (float*)d_out;

    const int N = in_sizes[0] / 128;   // 50000
    const int E = in_sizes[1];         // 800000

    char* ws = (char*)d_ws;
    size_t off = 0;
    auto alloc = [&](size_t bytes) -> void* {
        void* p = ws + off;
        off += (bytes + 255) & ~(size_t)255;
        return p;
    };
    int* deg_out  = (int*)alloc((size_t)N * 4);
    int* deg_in   = (int*)alloc((size_t)N * 4);
    int* row_ptr  = (int*)alloc((size_t)(N + 1) * 4);
    int* bsum     = (int*)alloc(SCAN_B * 4);
    int* rank     = (int*)alloc((size_t)E * 4);
    int2* edges   = (int2*)alloc((size_t)E * 8);
    float* inv_out = (float*)alloc((size_t)N * 4);
    float* inv_in  = (float*)alloc((size_t)N * 4);
    float* bufA = (float*)alloc((size_t)N * 128 * 4);   // G1, then G2
    float* bufB = (float*)alloc((size_t)N * 128 * 4);   // h1, then h2
    float* hd   = (float*)alloc((size_t)N * 256 * 4);

    // zero deg_out, deg_in (contiguous span)
    size_t zspan = (char*)deg_in + (size_t)N * 4 - (char*)deg_out;
    hipMemsetAsync(deg_out, 0, zspan, stream);

    int gE = (E + 255) / 256;
    int gN = (N + SCAN_B - 1) / SCAN_B;
    int gG = (N + 7) / 8;
    int gMM = (N + 127) / 128;         // MFMA M-tiles

    // fused launch: blocks [0,DEGB) = degree/rank atomics; rest = G1 = feat@W1.
    const int DEGB = 512;
    int epb = (E + DEGB - 1) / DEGB;
    k_gemm_mfma<128, 128, 2, true><<<DEGB + gMM * 2, 256, 0, stream>>>(
        feat, W1, nullptr, bufA, N, src, dst, deg_out, deg_in, rank, E, epb, gMM, DEGB);

    k_scanA<<<gN, SCAN_B, 0, stream>>>(deg_in, row_ptr, bsum, N);
    k_scanB<<<1, SCAN_B, 0, stream>>>(bsum, gN);
    k_scanC<<<gN, SCAN_B, 0, stream>>>(deg_in, deg_out, row_ptr, bsum, inv_in, inv_out, N, E);
    k_scatter3<<<gE, 256, 0, stream>>>(src, dst, row_ptr, rank, inv_out, edges, E);

    // layer 1 gather: h1 = relu(norm-agg(G1) + b1)
    k_gather2<<<gG, 256, 0, stream>>>(bufA, edges, row_ptr, inv_in, b1, bufB, N);
    // layer 2: G2 = h1 @ W2 ; h2 = relu(norm-agg(G2) + b2)
    k_gemm_mfma<128, 128, 2, false><<<dim3(gMM, 2), 256, 0, stream>>>(
        bufB, W2, nullptr, bufA, N, nullptr, nullptr, nullptr, nullptr, nullptr, 0, 0, 0, 0);
    k_gather2<<<gG, 256, 0, stream>>>(bufA, edges, row_ptr, inv_in, b2, bufB, N);
    // DNN
    k_gemm_mfma<128, 256, 1, false><<<dim3(gMM, 4), 256, 0, stream>>>(
        bufB, Wd1, bd1, hd, N, nullptr, nullptr, nullptr, nullptr, nullptr, 0, 0, 0, 0);
    k_gemm_mfma<256, 40, 1, false><<<dim3(gMM, 1), 256, 0, stream>>>(
        hd, Wd2, bd2, out, N, nullptr, nullptr, nullptr, nullptr, nullptr, 0, 0, 0, 0);
}